// Round 3
// baseline (508.048 us; speedup 1.0000x reference)
//
#include <hip/hip_runtime.h>
#include <stdint.h>

typedef __attribute__((ext_vector_type(8))) short short8;
typedef __attribute__((ext_vector_type(8))) unsigned short ushort8;
typedef __attribute__((ext_vector_type(4))) float floatx4;

#define BATCH 4096
#define HID   2048
#define KTOT  4096   // x-half (2048) then h-half (2048)

__device__ __forceinline__ uint16_t f2bf(float f) {
    union { uint32_t i; float f; } v; v.f = f;
    uint32_t u = v.i;
    u += 0x7fffu + ((u >> 16) & 1u);   // round-to-nearest-even
    return (uint16_t)(u >> 16);
}
__device__ __forceinline__ float sigmoid_f(float v) {
    return 1.0f / (1.0f + __expf(-v));
}
__device__ __forceinline__ float tanh_f(float v) {
    v = fminf(fmaxf(v, -15.0f), 15.0f);
    float e = __expf(-2.0f * v);
    return (1.0f - e) / (1.0f + e);
}
__device__ __forceinline__ void load_lds16(const uint16_t* g, uint16_t* l) {
    __builtin_amdgcn_global_load_lds(
        (const __attribute__((address_space(1))) void*)g,
        (__attribute__((address_space(3))) void*)l, 16, 0, 0);
}

// ===========================================================================
// Pre-pass 1: transpose+convert W (f32 K-major) -> wt bf16 [g][n][k4096].
// ===========================================================================
__global__ __launch_bounds__(256) void conv_w(
    const float* __restrict__ w0, const float* __restrict__ w1,
    const float* __restrict__ w2, const float* __restrict__ w3,
    const float* __restrict__ w4, const float* __restrict__ w5,
    const float* __restrict__ w6, const float* __restrict__ w7,
    uint16_t* __restrict__ wt)
{
    int b   = blockIdx.x;
    int mi  = b >> 8;           // matrix index = gate*2 + half
    int rem = b & 255;
    int k0  = (rem >> 4) * 128;
    int n0  = (rem & 15) * 128;
    const float* src;
    switch (mi) {
        case 0: src = w0; break; case 1: src = w1; break;
        case 2: src = w2; break; case 3: src = w3; break;
        case 4: src = w4; break; case 5: src = w5; break;
        case 6: src = w6; break; default: src = w7; break;
    }
    int g = mi >> 1, half = mi & 1;
    int ty = threadIdx.x >> 4, tx = threadIdx.x & 15;
    int kr = k0 + ty * 8;
    int nc = n0 + tx * 8;

    ushort8 a[8];
    #pragma unroll
    for (int j = 0; j < 8; ++j) {
        const float* s = src + (size_t)(kr + j) * HID + nc;
        floatx4 f0 = *(const floatx4*)(s);
        floatx4 f1 = *(const floatx4*)(s + 4);
        #pragma unroll
        for (int i = 0; i < 4; ++i) {
            a[j][i]     = f2bf(f0[i]);
            a[j][4 + i] = f2bf(f1[i]);
        }
    }
    ushort8 bt[8];
    #pragma unroll
    for (int i = 0; i < 8; ++i)
        #pragma unroll
        for (int j = 0; j < 8; ++j)
            bt[i][j] = a[j][i];
    #pragma unroll
    for (int i = 0; i < 8; ++i)
        *(ushort8*)(wt + ((size_t)g * HID + nc + i) * KTOT + half * HID + kr) = bt[i];
}

// ===========================================================================
// Pre-pass 2: pack [x | h] f32 -> xh bf16 [4096][4096] row-major.
// ===========================================================================
__global__ __launch_bounds__(256) void conv_a(
    const float* __restrict__ x, const float* __restrict__ h,
    uint16_t* __restrict__ xh)
{
    size_t base = ((size_t)blockIdx.x * 256 + threadIdx.x) * 8;
    int m = (int)(base >> 12);
    int k = (int)(base & (KTOT - 1));
    const float* s = (k < HID) ? (x + (size_t)m * HID + k)
                               : (h + (size_t)m * HID + (k - HID));
    floatx4 f0 = *(const floatx4*)(s);
    floatx4 f1 = *(const floatx4*)(s + 4);
    ushort8 v;
    #pragma unroll
    for (int j = 0; j < 4; ++j) { v[j] = f2bf(f0[j]); v[4 + j] = f2bf(f1[j]); }
    *(ushort8*)(xh + base) = v;
}

// ===========================================================================
// GEMM, 8-phase-class schedule (T3+T4+T5 on top of the proven T2 swizzle):
//  - tile: 256 M x (4 gates x 64 N), BK=64; 512 thr / 8 waves (2M x 4 gate-win)
//  - LDS 128 KiB: double-buffered A[256x64] + B[256x64] bf16, chunk-XOR
//    swizzled (phys 16B-chunk q of row r holds logical q ^ (r&7)); staging
//    pre-swizzles the GLOBAL source so global_load_lds dest stays lane-linear.
//  - 4 phases per K-tile: {ds_read frags; (P1 only: stage whole next tile,
//    8x global_load_lds w16 into the idle buffer); raw s_barrier; setprio(1);
//    16 MFMA; setprio(0); raw s_barrier}. Single vmcnt(0) per tile at P4-end,
//    3 phases after issue (issue-early/wait-late == counted wait here since
//    no younger loads exist at the wait point). Raw barriers avoid the
//    compiler's implicit vmcnt(0) drain that capped the previous structure.
//  - race-freedom: staging into buf d^1 is issued only after the barrier that
//    follows every wave's lgkmcnt(0) on its final reads of d^1 (prev tile P4);
//    vmcnt(0)-before-barrier at P4 publishes all threads' loads before any
//    wave's next-tile ds_reads.
//  - XCD swizzle (512 blocks, 512%8==0 -> bijective): each XCD gets 2 A-row
//    panels (2x2 MB, L2-resident) and streams B from L3.
// ===========================================================================

#define MFMA16(B0_)                                                           \
    __builtin_amdgcn_s_setprio(1);                                            \
    _Pragma("unroll") for (int i_ = 0; i_ < 4; ++i_)                          \
      _Pragma("unroll") for (int g_ = 0; g_ < 4; ++g_)                        \
        acc[(B0_) + i_][g_] = __builtin_amdgcn_mfma_f32_16x16x32_bf16(        \
            af[i_], bf[g_], acc[(B0_) + i_][g_], 0, 0, 0);                    \
    __builtin_amdgcn_s_setprio(0);

#define DO_TILE(RA, RB, SA, SB, K0S, DOSTAGE)                                 \
  {                                                                           \
    /* P1: B kh0 + A mi0-3 kh0; stage next tile into idle buffer */           \
    _Pragma("unroll") for (int g_ = 0; g_ < 4; ++g_)                          \
      bf[g_] = *(const short8*)((RB) + g_ * 4096 + pc0e);                     \
    _Pragma("unroll") for (int i_ = 0; i_ < 4; ++i_)                          \
      af[i_] = *(const short8*)((RA) + i_ * 1024 + pc0e);                     \
    if (DOSTAGE) {                                                            \
      _Pragma("unroll") for (int p_ = 0; p_ < 4; ++p_)                        \
        load_lds16(gA + (size_t)p_ * (64 * KTOT) + (K0S), (SA) + p_ * 4096);  \
      _Pragma("unroll") for (int p_ = 0; p_ < 4; ++p_)                        \
        load_lds16(gB + (size_t)p_ * ((size_t)HID * KTOT) + (K0S),            \
                   (SB) + p_ * 4096);                                         \
    }                                                                         \
    __builtin_amdgcn_s_barrier();                                             \
    MFMA16(0)                                                                 \
    __builtin_amdgcn_s_barrier();                                             \
    /* P2: A mi4-7 kh0 (B kh0 reused from registers) */                       \
    _Pragma("unroll") for (int i_ = 0; i_ < 4; ++i_)                          \
      af[i_] = *(const short8*)((RA) + (4 + i_) * 1024 + pc0e);               \
    __builtin_amdgcn_s_barrier();                                             \
    MFMA16(4)                                                                 \
    __builtin_amdgcn_s_barrier();                                             \
    /* P3: B kh1 + A mi0-3 kh1 */                                             \
    _Pragma("unroll") for (int g_ = 0; g_ < 4; ++g_)                          \
      bf[g_] = *(const short8*)((RB) + g_ * 4096 + pc1e);                     \
    _Pragma("unroll") for (int i_ = 0; i_ < 4; ++i_)                          \
      af[i_] = *(const short8*)((RA) + i_ * 1024 + pc1e);                     \
    __builtin_amdgcn_s_barrier();                                             \
    MFMA16(0)                                                                 \
    __builtin_amdgcn_s_barrier();                                             \
    /* P4: A mi4-7 kh1; publish staged tile before the phase barrier */       \
    _Pragma("unroll") for (int i_ = 0; i_ < 4; ++i_)                          \
      af[i_] = *(const short8*)((RA) + (4 + i_) * 1024 + pc1e);               \
    __builtin_amdgcn_s_barrier();                                             \
    MFMA16(4)                                                                 \
    asm volatile("s_waitcnt vmcnt(0)" ::: "memory");                          \
    __builtin_amdgcn_s_barrier();                                             \
  }

__global__ __launch_bounds__(512, 2) void lstm_gemm_bf16(
    const uint16_t* __restrict__ xh, const float* __restrict__ cx,
    const uint16_t* __restrict__ wt,
    const float* __restrict__ bvi, const float* __restrict__ bvf,
    const float* __restrict__ bvo, const float* __restrict__ bvc,
    float* __restrict__ out)
{
    // A0 @ 0, B0 @ 16384, A1 @ 32768, B1 @ 49152 (uint16 units) = 128 KiB
    __shared__ uint16_t lds[65536];

    int t = threadIdx.x;

    // XCD-aware bijective remap: 512 blocks, linear%8 = XCD
    int linear = blockIdx.x;
    int wg = (linear & 7) * 64 + (linear >> 3);
    int my = wg >> 5;                   // 0..15
    int nx = wg & 31;                   // 0..31
    int m0 = my * 256;
    int n0 = nx * 64;

    int wave = t >> 6, lane = t & 63;
    int wr = wave >> 2, wc = wave & 3;  // 2 M-halves x 4 gate-windows
    int lrow = lane & 15, quad = lane >> 4;
    int swz  = lrow & 7;

    // staging: per round 512 thr x 16 B = 64 rows x 128 B
    int srow = t >> 3;                  // 0..63
    int schk = (t & 7) ^ (srow & 7);    // pre-swizzled global chunk
    const uint16_t* gA = xh + (size_t)(m0 + srow) * KTOT + (size_t)schk * 8;
    const uint16_t* gB = wt + (size_t)(n0 + srow) * KTOT + (size_t)schk * 8;
    uint16_t* sA0 = lds + t * 8;
    uint16_t* sB0 = lds + 16384 + t * 8;
    uint16_t* sA1 = lds + 32768 + t * 8;
    uint16_t* sB1 = lds + 49152 + t * 8;

    // fragment-read bases (chunk-XOR swizzled)
    int aRow = wr * 128 + lrow;
    int bRow = wc * 16 + lrow;
    int pc0e = (quad ^ swz) * 8;         // kh0: logical chunk quad
    int pc1e = ((quad + 4) ^ swz) * 8;   // kh1: logical chunk quad+4
    const uint16_t* rA0 = lds + aRow * 64;
    const uint16_t* rB0 = lds + 16384 + bRow * 64;
    const uint16_t* rA1 = lds + 32768 + aRow * 64;
    const uint16_t* rB1 = lds + 49152 + bRow * 64;

    floatx4 acc[8][4] = {};              // [mi][gate]
    short8 af[4], bf[4];

    // prologue: stage tile 0 into buf0, drain, sync
    #pragma unroll
    for (int p = 0; p < 4; ++p)
        load_lds16(gA + (size_t)p * (64 * KTOT), sA0 + p * 4096);
    #pragma unroll
    for (int p = 0; p < 4; ++p)
        load_lds16(gB + (size_t)p * ((size_t)HID * KTOT), sB0 + p * 4096);
    asm volatile("s_waitcnt vmcnt(0)" ::: "memory");
    __builtin_amdgcn_s_barrier();

    for (int it = 0; it < 32; ++it) {
        size_t k0o = (size_t)it * 128 + 64;       // odd tile's k
        DO_TILE(rA0, rB0, sA1, sB1, k0o, true);         // even tile, stage odd
        DO_TILE(rA1, rB1, sA0, sB0, k0o + 64, it < 31); // odd tile, stage next even
    }

    // ---- fused LSTM epilogue (f32 in/out) ----
    int col = n0 + wc * 16 + lrow;
    float Bi = bvi[col], Bf = bvf[col], Bo = bvo[col], Bc = bvc[col];
    int rowb = m0 + wr * 128 + quad * 4;

    #pragma unroll
    for (int mi = 0; mi < 8; ++mi) {
        #pragma unroll
        for (int r = 0; r < 4; ++r) {
            int row = rowb + mi * 16 + r;
            size_t off = (size_t)row * HID + col;
            float gi = sigmoid_f(acc[mi][0][r] + Bi);
            float gf = sigmoid_f(acc[mi][1][r] + Bf);
            float go = sigmoid_f(acc[mi][2][r] + Bo);
            float gc = tanh_f   (acc[mi][3][r] + Bc);
            float cyv = gf * cx[off] + gi * gc;
            float hyv = go * tanh_f(cyv);
            out[off] = hyv;
            out[(size_t)BATCH * HID + off] = cyv;
        }
    }
}

// ===========================================================================
// Fallback (ws too small): Round-4 proven fused kernel, f32 inputs.
// ===========================================================================
__global__ __launch_bounds__(256) void lstm_fused_f32(
    const float* __restrict__ x, const float* __restrict__ h,
    const float* __restrict__ cx,
    const float* __restrict__ wxi, const float* __restrict__ whi,
    const float* __restrict__ wxf, const float* __restrict__ whf,
    const float* __restrict__ wxo, const float* __restrict__ who,
    const float* __restrict__ wxc, const float* __restrict__ whc,
    const float* __restrict__ bvi, const float* __restrict__ bvf,
    const float* __restrict__ bvo, const float* __restrict__ bvc,
    float* __restrict__ out)
{
    __shared__ uint16_t ldsA[128 * 32];
    __shared__ uint16_t ldsB[128 * 32];
    uint32_t* ldsB32 = (uint32_t*)ldsB;

    int t    = threadIdx.x;
    int n0   = blockIdx.x * 32;
    int m0   = blockIdx.y * 128;
    int wave = t >> 6, lane = t & 63;
    int wr = wave >> 1, wc = wave & 1;
    int lrow = lane & 15, quad = lane >> 4;
    int srow = t >> 2;
    int sseg = (t & 3) * 8;
    int gw = wave;
    int ng = lane & 3;
    int ka = lane >> 2;
    const float *wxg, *whg;
    switch (gw) {
        case 0:  wxg = wxi; whg = whi; break;
        case 1:  wxg = wxf; whg = whf; break;
        case 2:  wxg = wxo; whg = who; break;
        default: wxg = wxc; whg = whc; break;
    }

    floatx4 acc[4][4] = {};

    for (int kt = 0; kt < KTOT / 32; ++kt) {
        int k0  = kt * 32;
        int k0h = k0 & (HID - 1);
        bool xhalf = (k0 < HID);

        ushort8 va[2];
        uint32_t bw[8];
        const float* a = xhalf ? x : h;
        #pragma unroll
        for (int p = 0; p < 2; ++p) {
            const float* s = a + (size_t)(m0 + srow + p * 64) * HID + k0h + sseg;
            floatx4 f0 = *(const floatx4*)(s);
            floatx4 f1 = *(const floatx4*)(s + 4);
            #pragma unroll
            for (int j = 0; j < 4; ++j) {
                va[p][j]     = (short)f2bf(f0[j]);
                va[p][4 + j] = (short)f2bf(f1[j]);
            }
        }
        const float* wp  = xhalf ? wxg : whg;
        const float* r0p = wp + (size_t)(k0h + 2 * ka) * HID + n0 + ng * 8;
        floatx4 a0 = *(const floatx4*)(r0p);
        floatx4 a1 = *(const floatx4*)(r0p + 4);
        floatx4 b0 = *(const floatx4*)(r0p + HID);
        floatx4 b1 = *(const floatx4*)(r0p + HID + 4);
        #pragma unroll
        for (int j = 0; j < 4; ++j) {
            bw[j]     = (uint32_t)f2bf(a0[j]) | ((uint32_t)f2bf(b0[j]) << 16);
            bw[4 + j] = (uint32_t)f2bf(a1[j]) | ((uint32_t)f2bf(b1[j]) << 16);
        }

        __syncthreads();
        #pragma unroll
        for (int p = 0; p < 2; ++p)
            *(ushort8*)(ldsA + (srow + p * 64) * 32 + sseg) = va[p];
        #pragma unroll
        for (int j = 0; j < 8; ++j)
            ldsB32[(gw * 32 + ng * 8 + j) * 16 + ka] = bw[j];
        __syncthreads();

        short8 af[4], bfr[4];
        #pragma unroll
        for (int mi = 0; mi < 4; ++mi)
            af[mi] = *(const short8*)(ldsA + (wr * 64 + mi * 16 + lrow) * 32 + quad * 8);
        #pragma unroll
        for (int g = 0; g < 4; ++g)
            bfr[g] = *(const short8*)(ldsB + (g * 32 + wc * 16 + lrow) * 32 + quad * 8);

        #pragma unroll
        for (int mi = 0; mi < 4; ++mi)
            #pragma unroll
            for (int g = 0; g < 4; ++g)
                acc[mi][g] = __builtin_amdgcn_mfma_f32_16x16x32_bf16(
                    af[mi], bfr[g], acc[mi][g], 0, 0, 0);
    }

    int col = n0 + wc * 16 + lrow;
    float Bi = bvi[col], Bf = bvf[col], Bo = bvo[col], Bc = bvc[col];
    int rowb = m0 + wr * 64 + quad * 4;

    #pragma unroll
    for (int mi = 0; mi < 4; ++mi) {
        #pragma unroll
        for (int r = 0; r < 4; ++r) {
            int row = rowb + mi * 16 + r;
            size_t off = (size_t)row * HID + col;
            float gi = sigmoid_f(acc[mi][0][r] + Bi);
            float gf = sigmoid_f(acc[mi][1][r] + Bf);
            float go = sigmoid_f(acc[mi][2][r] + Bo);
            float gc = tanh_f   (acc[mi][3][r] + Bc);
            float cyv = gf * cx[off] + gi * gc;
            float hyv = go * tanh_f(cyv);
            out[off] = hyv;
            out[(size_t)BATCH * HID + off] = cyv;
        }
    }
}

extern "C" void kernel_launch(void* const* d_in, const int* in_sizes, int n_in,
                              void* d_out, int out_size, void* d_ws, size_t ws_size,
                              hipStream_t stream) {
    const float* x    = (const float*)d_in[0];
    const float* h_x  = (const float*)d_in[1];
    const float* c_x  = (const float*)d_in[2];
    const float* W_xi = (const float*)d_in[3];
    const float* W_hi = (const float*)d_in[4];
    const float* b_i  = (const float*)d_in[5];
    const float* W_xf = (const float*)d_in[6];
    const float* W_hf = (const float*)d_in[7];
    const float* b_f  = (const float*)d_in[8];
    const float* W_xc = (const float*)d_in[9];
    const float* W_hc = (const float*)d_in[10];
    const float* b_c  = (const float*)d_in[11];
    const float* W_xo = (const float*)d_in[12];
    const float* W_ho = (const float*)d_in[13];
    const float* b_o  = (const float*)d_in[14];

    const size_t WT_BYTES = (size_t)4 * HID * KTOT * sizeof(uint16_t); // 64 MiB
    const size_t XH_BYTES = (size_t)BATCH * KTOT * sizeof(uint16_t);   // 32 MiB

    if (ws_size >= WT_BYTES + XH_BYTES) {
        uint16_t* wt = (uint16_t*)d_ws;
        uint16_t* xh = (uint16_t*)((char*)d_ws + WT_BYTES);
        // gate order i,f,o,c
        hipLaunchKernelGGL(conv_w, dim3(8 * 256), dim3(256), 0, stream,
                           W_xi, W_hi, W_xf, W_hf, W_xo, W_ho, W_xc, W_hc, wt);
        hipLaunchKernelGGL(conv_a, dim3((BATCH * KTOT) / (256 * 8)), dim3(256), 0, stream,
                           x, h_x, xh);
        hipLaunchKernelGGL(lstm_gemm_bf16, dim3((BATCH / 256) * (HID / 64)), dim3(512), 0, stream,
                           xh, c_x, wt, b_i, b_f, b_o, b_c, (float*)d_out);
    } else {
        hipLaunchKernelGGL(lstm_fused_f32, dim3(HID / 32, BATCH / 128), dim3(256), 0, stream,
                           x, h_x, c_x,
                           W_xi, W_hi, W_xf, W_hf, W_xo, W_ho, W_xc, W_hc,
                           b_i, b_f, b_o, b_c, (float*)d_out);
    }
}

// Round 4
// 476.479 us; speedup vs baseline: 1.0663x; 1.0663x over previous
//
#include <hip/hip_runtime.h>
#include <stdint.h>

typedef __attribute__((ext_vector_type(8))) short short8;
typedef __attribute__((ext_vector_type(8))) unsigned short ushort8;
typedef __attribute__((ext_vector_type(4))) float floatx4;

#define BATCH 4096
#define HID   2048
#define KTOT  4096   // x-half (2048) then h-half (2048)

__device__ __forceinline__ uint16_t f2bf(float f) {
    union { uint32_t i; float f; } v; v.f = f;
    uint32_t u = v.i;
    u += 0x7fffu + ((u >> 16) & 1u);   // round-to-nearest-even
    return (uint16_t)(u >> 16);
}
__device__ __forceinline__ float sigmoid_f(float v) {
    return 1.0f / (1.0f + __expf(-v));
}
__device__ __forceinline__ float tanh_f(float v) {
    v = fminf(fmaxf(v, -15.0f), 15.0f);
    float e = __expf(-2.0f * v);
    return (1.0f - e) / (1.0f + e);
}
__device__ __forceinline__ void load_lds16(const uint16_t* g, uint16_t* l) {
    __builtin_amdgcn_global_load_lds(
        (const __attribute__((address_space(1))) void*)g,
        (__attribute__((address_space(3))) void*)l, 16, 0, 0);
}

// ===========================================================================
// Pre-pass 1: transpose+convert W (f32 K-major) -> wt bf16 [g][n][k4096].
// NEW: register 8x8 transpose -> LDS tile (16-chunk XOR swizzle, conflict-
// free per 16-lane quarter) -> 256 B contiguous global runs. Replaces the
// old scattered 16-B stores (lane stride 64 KB) that throttled write BW.
// ===========================================================================
__global__ __launch_bounds__(256) void conv_w(
    const float* __restrict__ w0, const float* __restrict__ w1,
    const float* __restrict__ w2, const float* __restrict__ w3,
    const float* __restrict__ w4, const float* __restrict__ w5,
    const float* __restrict__ w6, const float* __restrict__ w7,
    uint16_t* __restrict__ wt)
{
    __shared__ uint16_t tile[128 * 128];   // 32 KB: [n-row 0..127][k 0..127]

    int b   = blockIdx.x;
    int mi  = b >> 8;           // matrix index = gate*2 + half
    int rem = b & 255;
    int k0  = (rem >> 4) * 128;
    int n0  = (rem & 15) * 128;
    const float* src;
    switch (mi) {
        case 0: src = w0; break; case 1: src = w1; break;
        case 2: src = w2; break; case 3: src = w3; break;
        case 4: src = w4; break; case 5: src = w5; break;
        case 6: src = w6; break; default: src = w7; break;
    }
    int g = mi >> 1, half = mi & 1;
    int ty = threadIdx.x >> 4, tx = threadIdx.x & 15;
    int kr = k0 + ty * 8;
    int nc = n0 + tx * 8;

    ushort8 a[8];
    #pragma unroll
    for (int j = 0; j < 8; ++j) {
        const float* s = src + (size_t)(kr + j) * HID + nc;
        floatx4 f0 = *(const floatx4*)(s);
        floatx4 f1 = *(const floatx4*)(s + 4);
        #pragma unroll
        for (int i = 0; i < 4; ++i) {
            a[j][i]     = f2bf(f0[i]);
            a[j][4 + i] = f2bf(f1[i]);
        }
    }
    ushort8 bt[8];
    #pragma unroll
    for (int i = 0; i < 8; ++i)
        #pragma unroll
        for (int j = 0; j < 8; ++j)
            bt[i][j] = a[j][i];

    // LDS store: row = n-offset (tx*8+i), logical k-chunk = ty,
    // phys chunk = ty ^ (row>>3) = ty ^ tx. Per 16-lane quarter: ty fixed,
    // tx 0..15 -> (ty^tx)&7 covers 8 bank-groups x2 -> conflict-free.
    #pragma unroll
    for (int i = 0; i < 8; ++i)
        *(ushort8*)(tile + (tx * 8 + i) * 128 + ((ty ^ tx) & 15) * 8) = bt[i];
    __syncthreads();

    // Read back un-swizzled; 16 lanes x 16 B = 256 B contiguous per row.
    int t = threadIdx.x;
    #pragma unroll
    for (int p = 0; p < 8; ++p) {
        int r    = p * 16 + (t >> 4);          // n-row 0..127
        int lc   = t & 15;                     // logical k-chunk
        int phys = lc ^ ((r >> 3) & 15);
        ushort8 v = *(const ushort8*)(tile + r * 128 + phys * 8);
        *(ushort8*)(wt + ((size_t)g * HID + n0 + r) * KTOT
                       + half * HID + k0 + lc * 8) = v;
    }
}

// ===========================================================================
// Pre-pass 2: pack [x | h] f32 -> xh bf16 [4096][4096] row-major. (unchanged)
// ===========================================================================
__global__ __launch_bounds__(256) void conv_a(
    const float* __restrict__ x, const float* __restrict__ h,
    uint16_t* __restrict__ xh)
{
    size_t base = ((size_t)blockIdx.x * 256 + threadIdx.x) * 8;
    int m = (int)(base >> 12);
    int k = (int)(base & (KTOT - 1));
    const float* s = (k < HID) ? (x + (size_t)m * HID + k)
                               : (h + (size_t)m * HID + (k - HID));
    floatx4 f0 = *(const floatx4*)(s);
    floatx4 f1 = *(const floatx4*)(s + 4);
    ushort8 v;
    #pragma unroll
    for (int j = 0; j < 4; ++j) { v[j] = f2bf(f0[j]); v[4 + j] = f2bf(f1[j]); }
    *(ushort8*)(xh + base) = v;
}

// ===========================================================================
// GEMM: 256M x (4g x 64N) tile, BK=64, 512 thr / 8 waves, dbuf LDS 128 KiB.
// COUNTED-vmcnt pipeline (the m218 lever the last round missed):
//  - P1(t): ds_read kh0 frags; stage A(t+1) -> ALT buffer (dead since end of
//    tile t-1).
//  - P4(t): ds_read kh1 frags; stage B(t+2) -> CURRENT buffer's B region
//    (dead after P3(t)'s closing barrier, parity of t+2 == t).
//  - End of P4(t): s_waitcnt vmcnt(4) -- drains B(t+1)+A(t+1) (issued >=3
//    phases earlier), leaves B(t+2)'s 4 loads in flight ACROSS the barrier.
//    Never vmcnt(0) in the main loop. Epilogue: t=62 vmcnt(0), t=63 no stage.
//  - chunk-XOR LDS swizzle unchanged (bank conflicts measured 0).
//  - XCD remap: 2x4 XCD rectangles (8 my x 8 nx each): A fetched 4x, B 2x
//    -> ~256 MB ideal vs 557 MB measured last round.
// ===========================================================================

#define MFMA16(B0_)                                                           \
    __builtin_amdgcn_s_setprio(1);                                            \
    _Pragma("unroll") for (int i_ = 0; i_ < 4; ++i_)                          \
      _Pragma("unroll") for (int g_ = 0; g_ < 4; ++g_)                        \
        acc[(B0_) + i_][g_] = __builtin_amdgcn_mfma_f32_16x16x32_bf16(        \
            af[i_], bf[g_], acc[(B0_) + i_][g_], 0, 0, 0);                    \
    __builtin_amdgcn_s_setprio(0);

#define VM_WAIT4 asm volatile("s_waitcnt vmcnt(4)" ::: "memory")
#define VM_WAIT0 asm volatile("s_waitcnt vmcnt(0)" ::: "memory")
#define VM_NONE  ((void)0)

#define DO_TILE(RA, RB, SAN, SBC, KA, KB, DOA, DOB, VMOP)                     \
  {                                                                           \
    /* P1: B kh0 + A mi0-3 kh0; stage A(t+1) into alternate buffer */         \
    _Pragma("unroll") for (int g_ = 0; g_ < 4; ++g_)                          \
      bf[g_] = *(const short8*)((RB) + g_ * 4096 + pc0e);                     \
    _Pragma("unroll") for (int i_ = 0; i_ < 4; ++i_)                          \
      af[i_] = *(const short8*)((RA) + i_ * 1024 + pc0e);                     \
    if (DOA) {                                                                \
      _Pragma("unroll") for (int p_ = 0; p_ < 4; ++p_)                        \
        load_lds16(gA + (size_t)p_ * (64 * KTOT) + (KA), (SAN) + p_ * 4096);  \
    }                                                                         \
    __builtin_amdgcn_s_barrier();                                             \
    MFMA16(0)                                                                 \
    __builtin_amdgcn_s_barrier();                                             \
    /* P2: A mi4-7 kh0 (B kh0 reused from registers) */                       \
    _Pragma("unroll") for (int i_ = 0; i_ < 4; ++i_)                          \
      af[i_] = *(const short8*)((RA) + (4 + i_) * 1024 + pc0e);               \
    __builtin_amdgcn_s_barrier();                                             \
    MFMA16(4)                                                                 \
    __builtin_amdgcn_s_barrier();                                             \
    /* P3: B kh1 + A mi0-3 kh1 (last B reads of this buffer) */               \
    _Pragma("unroll") for (int g_ = 0; g_ < 4; ++g_)                          \
      bf[g_] = *(const short8*)((RB) + g_ * 4096 + pc1e);                     \
    _Pragma("unroll") for (int i_ = 0; i_ < 4; ++i_)                          \
      af[i_] = *(const short8*)((RA) + i_ * 1024 + pc1e);                     \
    __builtin_amdgcn_s_barrier();                                             \
    MFMA16(0)                                                                 \
    __builtin_amdgcn_s_barrier();                                             \
    /* P4: A mi4-7 kh1; stage B(t+2) into CURRENT buffer's dead B region */   \
    _Pragma("unroll") for (int i_ = 0; i_ < 4; ++i_)                          \
      af[i_] = *(const short8*)((RA) + (4 + i_) * 1024 + pc1e);               \
    if (DOB) {                                                                \
      _Pragma("unroll") for (int p_ = 0; p_ < 4; ++p_)                        \
        load_lds16(gB + (size_t)p_ * ((size_t)HID * KTOT) + (KB),             \
                   (SBC) + p_ * 4096);                                        \
    }                                                                         \
    __builtin_amdgcn_s_barrier();                                             \
    MFMA16(4)                                                                 \
    VMOP;                                                                     \
    __builtin_amdgcn_s_barrier();                                             \
  }

__global__ __launch_bounds__(512, 2) void lstm_gemm_bf16(
    const uint16_t* __restrict__ xh, const float* __restrict__ cx,
    const uint16_t* __restrict__ wt,
    const float* __restrict__ bvi, const float* __restrict__ bvf,
    const float* __restrict__ bvo, const float* __restrict__ bvc,
    float* __restrict__ out)
{
    // A0 @ 0, B0 @ 16384, A1 @ 32768, B1 @ 49152 (uint16 units) = 128 KiB
    __shared__ uint16_t lds[65536];

    int t = threadIdx.x;

    // XCD remap: 512 blocks; XCD = linear&7 arranged as 2x4 rectangle grid,
    // each XCD owns 8 my x 8 nx (A slice 16 MB, B slice 16 MB; k-window of
    // concurrent blocks fits the 4 MB L2).
    int linear = blockIdx.x;
    int xcd = linear & 7;
    int idx = linear >> 3;               // 0..63
    int my  = (xcd >> 2) * 8 + (idx >> 3);   // 0..15
    int nx  = (xcd & 3) * 8 + (idx & 7);     // 0..31
    int m0 = my * 256;
    int n0 = nx * 64;

    int wave = t >> 6, lane = t & 63;
    int wr = wave >> 2, wc = wave & 3;  // 2 M-halves x 4 gate-windows
    int lrow = lane & 15, quad = lane >> 4;
    int swz  = lrow & 7;

    // staging: per half-stage 512 thr x 16 B; 4 loads cover 256 rows x 64 k
    int srow = t >> 3;                  // 0..63
    int schk = (t & 7) ^ (srow & 7);    // pre-swizzled global chunk
    const uint16_t* gA = xh + (size_t)(m0 + srow) * KTOT + (size_t)schk * 8;
    const uint16_t* gB = wt + (size_t)(n0 + srow) * KTOT + (size_t)schk * 8;
    uint16_t* sA0 = lds + t * 8;
    uint16_t* sB0 = lds + 16384 + t * 8;
    uint16_t* sA1 = lds + 32768 + t * 8;
    uint16_t* sB1 = lds + 49152 + t * 8;

    // fragment-read bases (chunk-XOR swizzled)
    int aRow = wr * 128 + lrow;
    int bRow = wc * 16 + lrow;
    int pc0e = (quad ^ swz) * 8;         // kh0: logical chunk quad
    int pc1e = ((quad + 4) ^ swz) * 8;   // kh1: logical chunk quad+4
    const uint16_t* rA0 = lds + aRow * 64;
    const uint16_t* rB0 = lds + 16384 + bRow * 64;
    const uint16_t* rA1 = lds + 32768 + aRow * 64;
    const uint16_t* rB1 = lds + 49152 + bRow * 64;

    floatx4 acc[8][4] = {};              // [mi][gate]
    short8 af[4], bf[4];

    // prologue: stage A(0),B(0) -> buf0 and B(1) -> buf1; wait only the
    // first 8 (vmcnt(4) leaves B(1) in flight), sync.
    #pragma unroll
    for (int p = 0; p < 4; ++p)
        load_lds16(gA + (size_t)p * (64 * KTOT), sA0 + p * 4096);
    #pragma unroll
    for (int p = 0; p < 4; ++p)
        load_lds16(gB + (size_t)p * ((size_t)HID * KTOT), sB0 + p * 4096);
    #pragma unroll
    for (int p = 0; p < 4; ++p)
        load_lds16(gB + (size_t)p * ((size_t)HID * KTOT) + 64, sB1 + p * 4096);
    VM_WAIT4;
    __builtin_amdgcn_s_barrier();

    // main loop: tiles t=0..61 in pairs; queue: [B(t+1), A(t+1), B(t+2)],
    // end-of-tile vmcnt(4) keeps B(t+2) in flight.
    for (int it = 0; it < 31; ++it) {
        size_t kk = (size_t)it * 128;
        DO_TILE(rA0, rB0, sA1, sB0, kk + 64,  kk + 128, 1, 1, VM_WAIT4); // t=2it
        DO_TILE(rA1, rB1, sA0, sB1, kk + 128, kk + 192, 1, 1, VM_WAIT4); // t=2it+1
    }
    // t=62: stage A(63); drain everything (B(64) doesn't exist)
    DO_TILE(rA0, rB0, sA1, sB0, (size_t)63 * 64, 0, 1, 0, VM_WAIT0);
    // t=63: pure compute
    DO_TILE(rA1, rB1, sA0, sB1, 0, 0, 0, 0, VM_NONE);

    // ---- fused LSTM epilogue (f32 in/out) ----
    int col = n0 + wc * 16 + lrow;
    float Bi = bvi[col], Bf = bvf[col], Bo = bvo[col], Bc = bvc[col];
    int rowb = m0 + wr * 128 + quad * 4;

    #pragma unroll
    for (int mi = 0; mi < 8; ++mi) {
        #pragma unroll
        for (int r = 0; r < 4; ++r) {
            int row = rowb + mi * 16 + r;
            size_t off = (size_t)row * HID + col;
            float gi = sigmoid_f(acc[mi][0][r] + Bi);
            float gf = sigmoid_f(acc[mi][1][r] + Bf);
            float go = sigmoid_f(acc[mi][2][r] + Bo);
            float gc = tanh_f   (acc[mi][3][r] + Bc);
            float cyv = gf * cx[off] + gi * gc;
            float hyv = go * tanh_f(cyv);
            out[off] = hyv;
            out[(size_t)BATCH * HID + off] = cyv;
        }
    }
}

// ===========================================================================
// Fallback (ws too small): Round-4 proven fused kernel, f32 inputs.
// ===========================================================================
__global__ __launch_bounds__(256) void lstm_fused_f32(
    const float* __restrict__ x, const float* __restrict__ h,
    const float* __restrict__ cx,
    const float* __restrict__ wxi, const float* __restrict__ whi,
    const float* __restrict__ wxf, const float* __restrict__ whf,
    const float* __restrict__ wxo, const float* __restrict__ who,
    const float* __restrict__ wxc, const float* __restrict__ whc,
    const float* __restrict__ bvi, const float* __restrict__ bvf,
    const float* __restrict__ bvo, const float* __restrict__ bvc,
    float* __restrict__ out)
{
    __shared__ uint16_t ldsA[128 * 32];
    __shared__ uint16_t ldsB[128 * 32];
    uint32_t* ldsB32 = (uint32_t*)ldsB;

    int t    = threadIdx.x;
    int n0   = blockIdx.x * 32;
    int m0   = blockIdx.y * 128;
    int wave = t >> 6, lane = t & 63;
    int wr = wave >> 1, wc = wave & 1;
    int lrow = lane & 15, quad = lane >> 4;
    int srow = t >> 2;
    int sseg = (t & 3) * 8;
    int gw = wave;
    int ng = lane & 3;
    int ka = lane >> 2;
    const float *wxg, *whg;
    switch (gw) {
        case 0:  wxg = wxi; whg = whi; break;
        case 1:  wxg = wxf; whg = whf; break;
        case 2:  wxg = wxo; whg = who; break;
        default: wxg = wxc; whg = whc; break;
    }

    floatx4 acc[4][4] = {};

    for (int kt = 0; kt < KTOT / 32; ++kt) {
        int k0  = kt * 32;
        int k0h = k0 & (HID - 1);
        bool xhalf = (k0 < HID);

        ushort8 va[2];
        uint32_t bw[8];
        const float* a = xhalf ? x : h;
        #pragma unroll
        for (int p = 0; p < 2; ++p) {
            const float* s = a + (size_t)(m0 + srow + p * 64) * HID + k0h + sseg;
            floatx4 f0 = *(const floatx4*)(s);
            floatx4 f1 = *(const floatx4*)(s + 4);
            #pragma unroll
            for (int j = 0; j < 4; ++j) {
                va[p][j]     = (short)f2bf(f0[j]);
                va[p][4 + j] = (short)f2bf(f1[j]);
            }
        }
        const float* wp  = xhalf ? wxg : whg;
        const float* r0p = wp + (size_t)(k0h + 2 * ka) * HID + n0 + ng * 8;
        floatx4 a0 = *(const floatx4*)(r0p);
        floatx4 a1 = *(const floatx4*)(r0p + 4);
        floatx4 b0 = *(const floatx4*)(r0p + HID);
        floatx4 b1 = *(const floatx4*)(r0p + HID + 4);
        #pragma unroll
        for (int j = 0; j < 4; ++j) {
            bw[j]     = (uint32_t)f2bf(a0[j]) | ((uint32_t)f2bf(b0[j]) << 16);
            bw[4 + j] = (uint32_t)f2bf(a1[j]) | ((uint32_t)f2bf(b1[j]) << 16);
        }

        __syncthreads();
        #pragma unroll
        for (int p = 0; p < 2; ++p)
            *(ushort8*)(ldsA + (srow + p * 64) * 32 + sseg) = va[p];
        #pragma unroll
        for (int j = 0; j < 8; ++j)
            ldsB32[(gw * 32 + ng * 8 + j) * 16 + ka] = bw[j];
        __syncthreads();

        short8 af[4], bfr[4];
        #pragma unroll
        for (int mi = 0; mi < 4; ++mi)
            af[mi] = *(const short8*)(ldsA + (wr * 64 + mi * 16 + lrow) * 32 + quad * 8);
        #pragma unroll
        for (int g = 0; g < 4; ++g)
            bfr[g] = *(const short8*)(ldsB + (g * 32 + wc * 16 + lrow) * 32 + quad * 8);

        #pragma unroll
        for (int mi = 0; mi < 4; ++mi)
            #pragma unroll
            for (int g = 0; g < 4; ++g)
                acc[mi][g] = __builtin_amdgcn_mfma_f32_16x16x32_bf16(
                    af[mi], bfr[g], acc[mi][g], 0, 0, 0);
    }

    int col = n0 + wc * 16 + lrow;
    float Bi = bvi[col], Bf = bvf[col], Bo = bvo[col], Bc = bvc[col];
    int rowb = m0 + wr * 64 + quad * 4;

    #pragma unroll
    for (int mi = 0; mi < 4; ++mi) {
        #pragma unroll
        for (int r = 0; r < 4; ++r) {
            int row = rowb + mi * 16 + r;
            size_t off = (size_t)row * HID + col;
            float gi = sigmoid_f(acc[mi][0][r] + Bi);
            float gf = sigmoid_f(acc[mi][1][r] + Bf);
            float go = sigmoid_f(acc[mi][2][r] + Bo);
            float gc = tanh_f   (acc[mi][3][r] + Bc);
            float cyv = gf * cx[off] + gi * gc;
            float hyv = go * tanh_f(cyv);
            out[off] = hyv;
            out[(size_t)BATCH * HID + off] = cyv;
        }
    }
}

extern "C" void kernel_launch(void* const* d_in, const int* in_sizes, int n_in,
                              void* d_out, int out_size, void* d_ws, size_t ws_size,
                              hipStream_t stream) {
    const float* x    = (const float*)d_in[0];
    const float* h_x  = (const float*)d_in[1];
    const float* c_x  = (const float*)d_in[2];
    const float* W_xi = (const float*)d_in[3];
    const float* W_hi = (const float*)d_in[4];
    const float* b_i  = (const float*)d_in[5];
    const float* W_xf = (const float*)d_in[6];
    const float* W_hf = (const float*)d_in[7];
    const float* b_f  = (const float*)d_in[8];
    const float* W_xc = (const float*)d_in[9];
    const float* W_hc = (const float*)d_in[10];
    const float* b_c  = (const float*)d_in[11];
    const float* W_xo = (const float*)d_in[12];
    const float* W_ho = (const float*)d_in[13];
    const float* b_o  = (const float*)d_in[14];

    const size_t WT_BYTES = (size_t)4 * HID * KTOT * sizeof(uint16_t); // 64 MiB
    const size_t XH_BYTES = (size_t)BATCH * KTOT * sizeof(uint16_t);   // 32 MiB

    if (ws_size >= WT_BYTES + XH_BYTES) {
        uint16_t* wt = (uint16_t*)d_ws;
        uint16_t* xh = (uint16_t*)((char*)d_ws + WT_BYTES);
        // gate order i,f,o,c
        hipLaunchKernelGGL(conv_w, dim3(8 * 256), dim3(256), 0, stream,
                           W_xi, W_hi, W_xf, W_hf, W_xo, W_ho, W_xc, W_hc, wt);
        hipLaunchKernelGGL(conv_a, dim3((BATCH * KTOT) / (256 * 8)), dim3(256), 0, stream,
                           x, h_x, xh);
        hipLaunchKernelGGL(lstm_gemm_bf16, dim3((BATCH / 256) * (HID / 64)), dim3(512), 0, stream,
                           xh, c_x, wt, b_i, b_f, b_o, b_c, (float*)d_out);
    } else {
        hipLaunchKernelGGL(lstm_fused_f32, dim3(HID / 32, BATCH / 128), dim3(256), 0, stream,
                           x, h_x, c_x,
                           W_xi, W_hi, W_xf, W_hf, W_xo, W_ho, W_xc, W_hc,
                           b_i, b_f, b_o, b_c, (float*)d_out);
    }
}